// Round 1
// baseline (5866.240 us; speedup 1.0000x reference)
//
#include <hip/hip_runtime.h>

#define T_LEN 192
#define BATCH 16
#define HID 256

// workspace float offsets
#define OFF_X1    0
#define OFF_XPRE  3145728
#define OFF_BASE  6291456
#define OFF_HS    7077888
#define OFF_HT    7864320
#define OFF_HPART 7872512
#define OFF_CNT   7938048
#define OFF_RPART 7944384
#define OFF_ML    8009920
#define INIT_WORDS 80064   // ht(8192) + hpart(65536) + cnt(6336), contiguous

#define SMEM_BYTES 152192

__device__ __forceinline__ float bf2f(unsigned v){ return __uint_as_float(v << 16); }
__device__ __forceinline__ unsigned short f2bf(float f){
  unsigned u = __float_as_uint(f);
  u += 0x7fffu + ((u >> 16) & 1u);   // round-to-nearest-even
  return (unsigned short)(u >> 16);
}
__device__ __forceinline__ float tanh_f(float x){
  float cx = fminf(fmaxf(x, -15.f), 15.f);
  float e = __expf(2.f * cx);
  return (e - 1.f) / (e + 1.f);
}
__device__ __forceinline__ float sigm(float x){
  float cx = fminf(fmaxf(x, -30.f), 30.f);
  return 1.f / (1.f + __expf(-cx));
}

// cross-workgroup sync within a domain: counter reaches `target`
__device__ __forceinline__ void dsync(unsigned* c, unsigned target){
  __syncthreads();
  if (threadIdx.x == 0) {
    __threadfence();
    __hip_atomic_fetch_add(c, 1u, __ATOMIC_RELEASE, __HIP_MEMORY_SCOPE_AGENT);
    while (__hip_atomic_load(c, __ATOMIC_ACQUIRE, __HIP_MEMORY_SCOPE_AGENT) < target) {
      __builtin_amdgcn_s_sleep(1);
    }
    __threadfence();
  }
  __syncthreads();
}

__global__ __launch_bounds__(256) void initk(float* p, int n){
  int i = blockIdx.x * blockDim.x + threadIdx.x;
  int stride = gridDim.x * blockDim.x;
  for (; i < n; i += stride) p[i] = 0.f;
}

// out[r, c] (= or +=) sum_k A[r*256+k] * W[(c)*ldw + woff + k]  (+ bias[c])
// R = 3072 fixed via grid.y*16, K = 256 fixed. Tile: 16 rows x 32 cols.
__global__ __launch_bounds__(256) void proj(const float* __restrict__ A,
                                            const float* __restrict__ W,
                                            const float* __restrict__ bias,
                                            float* __restrict__ out,
                                            int C, int ldw, int woff, int accum){
  __shared__ float As[16 * 258];
  __shared__ float Wsh[256 * 34];
  const int tid = threadIdx.x;
  const int r0 = blockIdx.y * 16;
  const int c0 = blockIdx.x * 32;

  // load A tile: row i, k = tid
  for (int i = 0; i < 16; ++i)
    As[i * 258 + tid] = A[(r0 + i) * 256 + tid];
  // load W tile transposed: Wsh[k*34 + c]
  for (int i = 0; i < 32; ++i)
    Wsh[tid * 34 + i] = W[(c0 + i) * ldw + woff + tid];
  __syncthreads();

  const int r = tid >> 4;
  const int c2 = (tid & 15) * 2;
  float acc0 = 0.f, acc1 = 0.f;
  for (int k = 0; k < 256; k += 2) {
    float2 a  = *(const float2*)&As[r * 258 + k];
    float2 w0 = *(const float2*)&Wsh[k * 34 + c2];
    float2 w1 = *(const float2*)&Wsh[(k + 1) * 34 + c2];
    acc0 = fmaf(a.x, w0.x, acc0); acc0 = fmaf(a.y, w1.x, acc0);
    acc1 = fmaf(a.x, w0.y, acc1); acc1 = fmaf(a.y, w1.y, acc1);
  }
  const int rg = r0 + r;
  const int cg = c0 + c2;
  if (bias) { acc0 += bias[cg]; acc1 += bias[cg + 1]; }
  float* op = &out[rg * C + cg];
  if (accum) { float2 prev = *(const float2*)op; acc0 += prev.x; acc1 += prev.y; }
  float2 res; res.x = acc0; res.y = acc1;
  *(float2*)op = res;
}

// Shared LSTM: 32 WGs, WG w owns h-idx [8w, 8w+8) (=> 32 pre-cols across 4 gates)
// for all 16 batch rows. Flag-sync each step.
__global__ __launch_bounds__(256) void lstm_kernel(const float* __restrict__ X1,
                                                   const float* __restrict__ W_hh,
                                                   float* __restrict__ hs,
                                                   unsigned* __restrict__ cnt){
  __shared__ float Wl[32 * 260];
  __shared__ float hl[256 * 16];
  __shared__ float prel[32 * 17];
  __shared__ float cl[8 * 16];
  const int tid = threadIdx.x;
  const int w = blockIdx.x;

  // load weight slice: Wl[l][k], l -> global pre-col gate*256 + 8w + jj
  for (int i = 0; i < 32; ++i) {
    int gate = i >> 3, jj = i & 7;
    int row = gate * 256 + 8 * w + jj;
    Wl[i * 260 + tid] = W_hh[row * 256 + tid];
  }
  if (tid < 128) cl[tid] = 0.f;
  __syncthreads();

  const int b2 = tid & 7;
  const int l = tid >> 3;
  const int b0 = 2 * b2;
  const int gate = l >> 3, jj = l & 7;
  const int colg = gate * 256 + 8 * w + jj;

  for (int t = 0; t < T_LEN; ++t) {
    // stage a: load h_prev -> hl[k][b]
    if (t == 0) {
      for (int i = 0; i < 16; ++i) hl[tid + i * 256] = 0.f;
    } else {
      for (int i = 0; i < 16; ++i) {
        int idx = tid + i * 256;
        int b = idx >> 8, j = idx & 255;
        hl[j * 16 + b] = hs[((t - 1) * 16 + b) * 256 + j];
      }
    }
    __syncthreads();

    // stage b: pre = X1 + W_hh * h_prev (2 batch rows per thread)
    float acc0 = X1[(t * 16 + b0) * 1024 + colg];
    float acc1 = X1[(t * 16 + b0 + 1) * 1024 + colg];
    for (int k = 0; k < 256; k += 4) {
      float4 wv = *(const float4*)&Wl[l * 260 + k];
      float2 h0 = *(const float2*)&hl[(k + 0) * 16 + b0];
      float2 h1 = *(const float2*)&hl[(k + 1) * 16 + b0];
      float2 h2 = *(const float2*)&hl[(k + 2) * 16 + b0];
      float2 h3 = *(const float2*)&hl[(k + 3) * 16 + b0];
      acc0 = fmaf(wv.x, h0.x, acc0); acc0 = fmaf(wv.y, h1.x, acc0);
      acc0 = fmaf(wv.z, h2.x, acc0); acc0 = fmaf(wv.w, h3.x, acc0);
      acc1 = fmaf(wv.x, h0.y, acc1); acc1 = fmaf(wv.y, h1.y, acc1);
      acc1 = fmaf(wv.z, h2.y, acc1); acc1 = fmaf(wv.w, h3.y, acc1);
    }
    prel[l * 17 + b0] = acc0;
    prel[l * 17 + b0 + 1] = acc1;
    __syncthreads();

    // stage c: gates + h write (128 threads: b = tid&15, jj = tid>>4)
    if (tid < 128) {
      int b = tid & 15, j = tid >> 4;
      float pi = prel[(0  + j) * 17 + b];
      float pf = prel[(8  + j) * 17 + b];
      float pg = prel[(16 + j) * 17 + b];
      float po = prel[(24 + j) * 17 + b];
      float co = cl[j * 16 + b];
      float ig = sigm(pi), fg = sigm(pf), gg = tanh_f(pg), og = sigm(po);
      float cn = fmaf(fg, co, ig * gg);
      float h = og * tanh_f(cn);
      cl[j * 16 + b] = cn;
      hs[(t * 16 + b) * 256 + 8 * w + j] = h;
    }
    dsync(&cnt[t], 32);
  }
}

// Task loop: 128 WGs; WG = (b = bid>>3, s = bid&7). Owns h-idx [32s,32s+32) of batch b.
__global__ __launch_bounds__(256) void task_kernel(
    const float* __restrict__ base, const float* __restrict__ xpre,
    const float* __restrict__ hs, const float* __restrict__ Us_w,
    const float* __restrict__ Us_b, const float* __restrict__ Wc,
    const float* __restrict__ Ws_w, float* __restrict__ ht,
    float* __restrict__ hpart, float* __restrict__ rpart, float* __restrict__ ml,
    unsigned* __restrict__ cnt, float* __restrict__ out){
  extern __shared__ char smem[];
  unsigned short* WcS  = (unsigned short*)smem;            // 128x512 bf16, interleaved
  unsigned short* Ws2S = (unsigned short*)(smem + 131072); // 256x32 bf16
  float* act   = (float*)(smem + 147456);  // [Rt(256), hh(256)]
  float* hterm = (float*)(smem + 149504);
  float* prel  = (float*)(smem + 150528);  // 128 x 2 halves
  float* sc    = (float*)(smem + 151552);  // 24 scores
  float* ee    = (float*)(smem + 151680);  // 24 exps
  float* hnew  = (float*)(smem + 151808);  // 32
  float* cst   = (float*)(smem + 151936);  // 32
  float* esc   = (float*)(smem + 152064);  // 8
  float* msc   = (float*)(smem + 152128);  // scratch

  const int tid = threadIdx.x;
  const int b = blockIdx.x >> 3;
  const int s = blockIdx.x & 7;

  // load Wc slice (cols 256..768 of its 128 pre-cols) as bf16, interleaved [(k>>2)*128 + l]*4 + (k&3)
  for (int i = 0; i < 256; ++i) {
    int idx = tid + i * 256;          // 0..65535
    int l = idx >> 9, k = idx & 511;
    int gate = l >> 5, jl = l & 31;
    int row = gate * 256 + 32 * s + jl;
    WcS[((k >> 2) * 128 + l) * 4 + (k & 3)] = f2bf(Wc[row * 768 + 256 + k]);
  }
  // load Ws2 slice: [c][k], k in [32s, 32s+32)
  for (int i = 0; i < 32; ++i) {
    int idx = tid + i * 256;          // 0..8191
    int c = idx >> 5, k = idx & 31;
    Ws2S[c * 32 + k] = f2bf(Ws_w[c * 768 + 256 + 32 * s + k]);
  }
  if (tid < 32) cst[tid] = 0.f;
  __syncthreads();

  const uint2* wp = (const uint2*)WcS;
  const unsigned* w2 = (const unsigned*)Ws2S;

  for (int t = 0; t < T_LEN; ++t) {
    const int par = t & 1;

    // ---------------- stage 2 ----------------
    // sum hterm partials (written by stage3(t-1) into buf[par]; buf[0] zero-initialized)
    {
      float hsum = 0.f;
      for (int i = 0; i < 8; ++i)
        hsum += hpart[((par * 16 + b) * 8 + i) * 256 + tid];
      hterm[tid] = hsum;
    }
    __syncthreads();

    // scores for 24 rows t' = 24s .. 24s+23 (wave wv handles 6 rows)
    {
      int wv = tid >> 6, lane = tid & 63;
      for (int q = 0; q < 6; ++q) {
        int tp = 24 * s + wv * 6 + q;
        float4 bs = *(const float4*)&base[(tp * 16 + b) * 256 + lane * 4];
        float4 h4 = *(const float4*)&hterm[lane * 4];
        float4 u4 = *(const float4*)&Us_w[lane * 4];
        float p = u4.x * tanh_f(bs.x + h4.x) + u4.y * tanh_f(bs.y + h4.y)
                + u4.z * tanh_f(bs.z + h4.z) + u4.w * tanh_f(bs.w + h4.w);
        for (int off = 32; off >= 1; off >>= 1) p += __shfl_xor(p, off);
        if (lane == 0) sc[wv * 6 + q] = p + Us_b[0];
      }
    }
    __syncthreads();

    // local softmax partials over 24 scores
    if (tid == 0) {
      float m = sc[0];
      for (int i = 1; i < 24; ++i) m = fmaxf(m, sc[i]);
      msc[0] = m;
    }
    __syncthreads();
    if (tid < 24) ee[tid] = __expf(sc[tid] - msc[0]);
    __syncthreads();
    if (tid == 0) {
      float lsum = 0.f;
      for (int i = 0; i < 24; ++i) lsum += ee[i];
      ml[((par * 16 + b) * 8 + s) * 2 + 0] = msc[0];
      ml[((par * 16 + b) * 8 + s) * 2 + 1] = lsum;
    }
    // R partial: R[c] = sum_q ee[q] * hs[t'][b][c]
    {
      float r = 0.f;
      for (int q = 0; q < 24; ++q)
        r = fmaf(ee[q], hs[((24 * s + q) * 16 + b) * 256 + tid], r);
      rpart[((par * 16 + b) * 8 + s) * 256 + tid] = r;
    }
    dsync(&cnt[(b * 192 + t) * 2 + 0], 8);

    // ---------------- stage 3 ----------------
    if (tid == 0) {
      float M = -1e30f;
      for (int i = 0; i < 8; ++i) M = fmaxf(M, ml[((par * 16 + b) * 8 + i) * 2]);
      float L = 0.f;
      for (int i = 0; i < 8; ++i) {
        float e = __expf(ml[((par * 16 + b) * 8 + i) * 2] - M);
        esc[i] = e;
        L += e * ml[((par * 16 + b) * 8 + i) * 2 + 1];
      }
      msc[2] = 1.f / L;
    }
    __syncthreads();
    {
      float rt = 0.f;
      for (int i = 0; i < 8; ++i)
        rt = fmaf(esc[i], rpart[((par * 16 + b) * 8 + i) * 256 + tid], rt);
      act[tid] = rt * msc[2];
      act[256 + tid] = ht[(par * 16 + b) * 256 + tid];
    }
    __syncthreads();

    // gates: pre-col l = tid&127 (gate = l>>5, jl = l&31), half = tid>>7 of K=512
    {
      int l = tid & 127, half = tid >> 7;
      int gate = l >> 5, jl = l & 31;
      float acc = (half == 0) ? xpre[(t * 16 + b) * 1024 + gate * 256 + 32 * s + jl] : 0.f;
      int kbase = half * 256;
      for (int kk = 0; kk < 256; kk += 4) {
        int k = kbase + kk;
        uint2 wv = wp[(k >> 2) * 128 + l];
        float4 av = *(const float4*)&act[k];
        acc = fmaf(bf2f(wv.x & 0xffffu), av.x, acc);
        acc = fmaf(bf2f(wv.x >> 16),     av.y, acc);
        acc = fmaf(bf2f(wv.y & 0xffffu), av.z, acc);
        acc = fmaf(bf2f(wv.y >> 16),     av.w, acc);
      }
      prel[l * 2 + half] = acc;
    }
    __syncthreads();

    if (tid < 32) {
      int jl = tid;
      float pi = prel[(0   + jl) * 2] + prel[(0   + jl) * 2 + 1];
      float pf = prel[(32  + jl) * 2] + prel[(32  + jl) * 2 + 1];
      float pg = prel[(64  + jl) * 2] + prel[(64  + jl) * 2 + 1];
      float po = prel[(96  + jl) * 2] + prel[(96  + jl) * 2 + 1];
      float co = cst[jl];
      float ig = sigm(pi), fg = sigm(pf), gg = tanh_f(pg), og = sigm(po);
      float cn = fmaf(fg, co, ig * gg);
      float h = og * tanh_f(cn);
      cst[jl] = cn; hnew[jl] = h;
      ht[((1 - par) * 16 + b) * 256 + 32 * s + jl] = h;
      out[(b * 192 + t) * 256 + 32 * s + jl] = h;
    }
    __syncthreads();

    // hterm partial for next step from own h-slice
    {
      float p = 0.f;
      for (int k = 0; k < 32; k += 2) {
        unsigned v = w2[(tid * 32 + k) >> 1];
        p = fmaf(bf2f(v & 0xffffu), hnew[k], p);
        p = fmaf(bf2f(v >> 16), hnew[k + 1], p);
      }
      hpart[(((1 - par) * 16 + b) * 8 + s) * 256 + tid] = p;
    }
    dsync(&cnt[(b * 192 + t) * 2 + 1], 8);
  }
}

extern "C" void kernel_launch(void* const* d_in, const int* in_sizes, int n_in,
                              void* d_out, int out_size, void* d_ws, size_t ws_size,
                              hipStream_t stream) {
  (void)in_sizes; (void)n_in; (void)out_size; (void)ws_size;
  const float* x    = (const float*)d_in[0];
  const float* W_ih = (const float*)d_in[1];
  const float* W_hh = (const float*)d_in[2];
  const float* b_l  = (const float*)d_in[3];
  const float* Ws_w = (const float*)d_in[4];
  const float* Ws_b = (const float*)d_in[5];
  const float* Us_w = (const float*)d_in[6];
  const float* Us_b = (const float*)d_in[7];
  const float* Wc   = (const float*)d_in[8];
  const float* bc   = (const float*)d_in[9];
  float* out = (float*)d_out;
  float* ws = (float*)d_ws;

  hipFuncSetAttribute((const void*)task_kernel,
                      hipFuncAttributeMaxDynamicSharedMemorySize, 160 * 1024);

  // zero sync counters + hterm-partial buf0 + ht buf0
  initk<<<64, 256, 0, stream>>>(ws + OFF_HT, INIT_WORDS);

  // X1 = x @ W_ih.T + b_lstm
  proj<<<dim3(32, 192), 256, 0, stream>>>(x, W_ih, b_l, ws + OFF_X1, 1024, 256, 0, 0);
  // xpre = x @ Wc[:, 0:256].T + bc
  proj<<<dim3(32, 192), 256, 0, stream>>>(x, Wc, bc, ws + OFF_XPRE, 1024, 768, 0, 0);
  // base = x @ Ws_w[:, 512:768].T + Ws_b
  proj<<<dim3(8, 192), 256, 0, stream>>>(x, Ws_w, Ws_b, ws + OFF_BASE, 256, 768, 512, 0);

  // shared LSTM -> hs
  lstm_kernel<<<32, 256, 0, stream>>>(ws + OFF_X1, W_hh, ws + OFF_HS,
                                      (unsigned*)(ws + OFF_CNT));

  // base += hs @ Ws_w[:, 0:256].T
  proj<<<dim3(8, 192), 256, 0, stream>>>(ws + OFF_HS, Ws_w, nullptr, ws + OFF_BASE, 256, 768, 0, 1);

  // task loop
  task_kernel<<<128, 256, SMEM_BYTES, stream>>>(
      ws + OFF_BASE, ws + OFF_XPRE, ws + OFF_HS, Us_w, Us_b, Wc, Ws_w,
      ws + OFF_HT, ws + OFF_HPART, ws + OFF_RPART, ws + OFF_ML,
      (unsigned*)(ws + OFF_CNT) + 192, out);
}

// Round 2
// 2585.771 us; speedup vs baseline: 2.2687x; 2.2687x over previous
//
#include <hip/hip_runtime.h>
#include <hip/hip_fp16.h>

#define T_LEN 192

// workspace float offsets
#define OFF_X1    0
#define OFF_XPRE  3145728
#define OFF_BASE  6291456
#define OFF_HS    7077888
// exchange region (contiguous, zeroed by initk each launch)
#define OFF_HT    7864320   // f32 [2][16][256]
#define OFF_HTERM 7872512   // f32 [2][16][256]
#define OFF_RBUF  7880704   // f32 [2][16][256]
#define OFF_LBUF  7888896   // f32 [2][16]
#define OFF_HX    7888928   // u32 [2][2048]  (lstm h exchange, half2)
#define OFF_CNT   7893024   // u32 [192 + 16*192*2]
#define INIT_WORDS 35040

#define SMEM_TASK 152064

typedef _Float16 h2_t __attribute__((ext_vector_type(2)));

__device__ __forceinline__ unsigned packh2(float a, float b){
  union { __half2 h; unsigned u; } v;
  v.h = __halves2half2(__float2half(a), __float2half(b));
  return v.u;
}
__device__ __forceinline__ float fdot2(unsigned a, unsigned b, float c){
#if __has_builtin(__builtin_amdgcn_fdot2)
  union { unsigned u; h2_t h; } ua, ub;
  ua.u = a; ub.u = b;
  return __builtin_amdgcn_fdot2(ua.h, ub.h, c, false);
#else
  union { unsigned u; __half2 h; } ua, ub;
  ua.u = a; ub.u = b;
  return c + __low2float(ua.h) * __low2float(ub.h)
           + __high2float(ua.h) * __high2float(ub.h);
#endif
}
__device__ __forceinline__ float tanh_f(float x){
  float cx = fminf(fmaxf(x, -15.f), 15.f);
  float e = __expf(2.f * cx);
  return (e - 1.f) / (e + 1.f);
}
__device__ __forceinline__ float sigm(float x){
  float cx = fminf(fmaxf(x, -30.f), 30.f);
  return 1.f / (1.f + __expf(-cx));
}

// relaxed agent-scope atomics: coherent at L3, NO cache-maintenance (no L2 inv/wb)
__device__ __forceinline__ float gldf(const float* p){
  return __hip_atomic_load(p, __ATOMIC_RELAXED, __HIP_MEMORY_SCOPE_AGENT);
}
__device__ __forceinline__ unsigned gldu(const unsigned* p){
  return __hip_atomic_load(p, __ATOMIC_RELAXED, __HIP_MEMORY_SCOPE_AGENT);
}
__device__ __forceinline__ void gstf(float* p, float v){
  __hip_atomic_store(p, v, __ATOMIC_RELAXED, __HIP_MEMORY_SCOPE_AGENT);
}
__device__ __forceinline__ void gstu(unsigned* p, unsigned v){
  __hip_atomic_store(p, v, __ATOMIC_RELAXED, __HIP_MEMORY_SCOPE_AGENT);
}
__device__ __forceinline__ void gaddf(float* p, float v){
  __hip_atomic_fetch_add(p, v, __ATOMIC_RELAXED, __HIP_MEMORY_SCOPE_AGENT);
}

// cross-WG barrier: __syncthreads() drains vmcnt(0) before s_barrier, so all
// prior (atomic, write-through) stores have reached the coherence point.
__device__ __forceinline__ void dsyncA(unsigned* c, unsigned target){
  __syncthreads();
  if (threadIdx.x == 0) {
    __hip_atomic_fetch_add(c, 1u, __ATOMIC_RELAXED, __HIP_MEMORY_SCOPE_AGENT);
    while (__hip_atomic_load(c, __ATOMIC_RELAXED, __HIP_MEMORY_SCOPE_AGENT) < target)
      __builtin_amdgcn_s_sleep(1);
    __atomic_signal_fence(__ATOMIC_SEQ_CST);
  }
  __syncthreads();
}

__global__ __launch_bounds__(256) void initk(float* p, int n){
  int i = blockIdx.x * blockDim.x + threadIdx.x;
  int stride = gridDim.x * blockDim.x;
  for (; i < n; i += stride) p[i] = 0.f;
}

// out[r, c] (= or +=) sum_k A[r*256+k] * W[c*ldw + woff + k]  (+ bias[c])
__global__ __launch_bounds__(256) void proj(const float* __restrict__ A,
                                            const float* __restrict__ W,
                                            const float* __restrict__ bias,
                                            float* __restrict__ out,
                                            int C, int ldw, int woff, int accum){
  __shared__ float As[16 * 258];
  __shared__ float Wsh[256 * 34];
  const int tid = threadIdx.x;
  const int r0 = blockIdx.y * 16;
  const int c0 = blockIdx.x * 32;

  for (int i = 0; i < 16; ++i)
    As[i * 258 + tid] = A[(r0 + i) * 256 + tid];
  for (int i = 0; i < 32; ++i)
    Wsh[tid * 34 + i] = W[(c0 + i) * ldw + woff + tid];
  __syncthreads();

  const int r = tid >> 4;
  const int c2 = (tid & 15) * 2;
  float acc0 = 0.f, acc1 = 0.f;
  for (int k = 0; k < 256; k += 2) {
    float2 a  = *(const float2*)&As[r * 258 + k];
    float2 w0 = *(const float2*)&Wsh[k * 34 + c2];
    float2 w1 = *(const float2*)&Wsh[(k + 1) * 34 + c2];
    acc0 = fmaf(a.x, w0.x, acc0); acc0 = fmaf(a.y, w1.x, acc0);
    acc1 = fmaf(a.x, w0.y, acc1); acc1 = fmaf(a.y, w1.y, acc1);
  }
  const int rg = r0 + r;
  const int cg = c0 + c2;
  if (bias) { acc0 += bias[cg]; acc1 += bias[cg + 1]; }
  float* op = &out[rg * C + cg];
  if (accum) { float2 prev = *(const float2*)op; acc0 += prev.x; acc1 += prev.y; }
  float2 res; res.x = acc0; res.y = acc1;
  *(float2*)op = res;
}

// Shared LSTM: 32 WGs, WG w owns h-cols [8w, 8w+8) for all 16 batch rows.
// f16 weights in LDS, v_dot2 accumulate in f32; h exchanged as packed half2
// via relaxed agent atomics (hx), plus f32 hs for downstream kernels.
__global__ __launch_bounds__(256) void lstm_kernel(const float* __restrict__ X1,
                                                   const float* __restrict__ W_hh,
                                                   float* __restrict__ hs,
                                                   unsigned* __restrict__ hx,
                                                   unsigned* __restrict__ cnt){
  __shared__ unsigned Wl2[32 * 136];  // [l][k2] f16x2, pad 136 (16B-aligned rows)
  __shared__ unsigned hl2[16 * 136];  // [b][k2] f16x2
  __shared__ float prel[32 * 17];
  __shared__ float cl[128];
  __shared__ float hsl[128];
  const int tid = threadIdx.x;
  const int w = blockIdx.x;

  // weight fill: l in [0,32) -> pre-col (l>>3)*256 + 8w + (l&7); k2 pairs K
  for (int i = 0; i < 16; ++i) {
    int idx = tid + i * 256;            // 0..4095
    int l = idx >> 7, k2 = idx & 127;
    int row = (l >> 3) * 256 + 8 * w + (l & 7);
    Wl2[l * 136 + k2] = packh2(W_hh[row * 256 + 2 * k2], W_hh[row * 256 + 2 * k2 + 1]);
  }
  if (tid < 128) cl[tid] = 0.f;
  __syncthreads();

  const int l0 = tid >> 4;      // 0..15
  const int l1 = l0 + 16;
  const int bb = tid & 15;
  const int colg0 = (l0 >> 3) * 256 + 8 * w + (l0 & 7);
  const int colg1 = (l1 >> 3) * 256 + 8 * w + (l1 & 7);

  for (int t = 0; t < T_LEN; ++t) {
    const int par = t & 1;

    // stage a: h_prev (packed) -> LDS
    if (t == 0) {
      for (int i = 0; i < 8; ++i) {
        int idx = tid + i * 256;
        hl2[(idx & 15) * 136 + (idx >> 4)] = 0u;
      }
    } else {
      for (int i = 0; i < 8; ++i) {
        int idx = tid + i * 256;        // k2g = idx>>4, b = idx&15
        hl2[(idx & 15) * 136 + (idx >> 4)] = gldu(&hx[par * 2048 + idx]);
      }
    }
    float acc0 = X1[(t * 16 + bb) * 1024 + colg0];
    float acc1 = X1[(t * 16 + bb) * 1024 + colg1];
    __syncthreads();

    // stage b: dot2 GEMV, 2 pre-cols per thread
    {
      const uint4* wv0 = (const uint4*)&Wl2[l0 * 136];
      const uint4* wv1 = (const uint4*)&Wl2[l1 * 136];
      const uint4* hv  = (const uint4*)&hl2[bb * 136];
      for (int q = 0; q < 32; ++q) {
        uint4 h4 = hv[q];
        uint4 a4 = wv0[q];
        uint4 b4 = wv1[q];
        acc0 = fdot2(a4.x, h4.x, acc0); acc0 = fdot2(a4.y, h4.y, acc0);
        acc0 = fdot2(a4.z, h4.z, acc0); acc0 = fdot2(a4.w, h4.w, acc0);
        acc1 = fdot2(b4.x, h4.x, acc1); acc1 = fdot2(b4.y, h4.y, acc1);
        acc1 = fdot2(b4.z, h4.z, acc1); acc1 = fdot2(b4.w, h4.w, acc1);
      }
      prel[l0 * 17 + bb] = acc0;
      prel[l1 * 17 + bb] = acc1;
    }
    __syncthreads();

    // stage c: gates + h
    if (tid < 128) {
      int b = tid & 15, j = tid >> 4;
      float pi = prel[(0  + j) * 17 + b];
      float pf = prel[(8  + j) * 17 + b];
      float pg = prel[(16 + j) * 17 + b];
      float po = prel[(24 + j) * 17 + b];
      float co = cl[j * 16 + b];
      float ig = sigm(pi), fg = sigm(pf), gg = tanh_f(pg), og = sigm(po);
      float cn = fmaf(fg, co, ig * gg);
      float h = og * tanh_f(cn);
      cl[j * 16 + b] = cn;
      hsl[j * 16 + b] = h;
      hs[(t * 16 + b) * 256 + 8 * w + j] = h;
    }
    __syncthreads();
    if (tid < 64) {
      int jp = tid >> 4, b = tid & 15;
      gstu(&hx[(1 - par) * 2048 + (4 * w + jp) * 16 + b],
           packh2(hsl[(2 * jp) * 16 + b], hsl[(2 * jp + 1) * 16 + b]));
    }
    dsyncA(&cnt[t], 32);
  }
}

// Task loop: 128 WGs; b = bid&15 (co-XCD domain since XCD = bid%8), s = bid>>4.
// WG owns h-cols [32s,32s+32) of batch b. 2 relaxed-atomic syncs/step.
__global__ __launch_bounds__(256) void task_kernel(
    const float* __restrict__ base, const float* __restrict__ xpre,
    const float* __restrict__ hs, const float* __restrict__ Us_w,
    const float* __restrict__ Us_b, const float* __restrict__ Wc,
    const float* __restrict__ Ws_w, float* __restrict__ ht,
    float* __restrict__ htermbuf, float* __restrict__ rbuf,
    float* __restrict__ lbuf, unsigned* __restrict__ cnt,
    float* __restrict__ out){
  extern __shared__ char smem[];
  unsigned* WcH   = (unsigned*)smem;              // 131072 B: [(k2q*128+l)*4 + j]
  unsigned* W2H   = (unsigned*)(smem + 131072);   // 16384 B: [k2*256 + c]
  unsigned* actH  = (unsigned*)(smem + 147456);   // 1024 B: [k2] half2 of act
  float* hterml   = (float*)(smem + 148480);      // 256
  float* usl      = (float*)(smem + 149504);      // 256
  float* eel      = (float*)(smem + 150528);      // 24 (pad 32)
  float* prel     = (float*)(smem + 150656);      // 128 x 2
  float* hnewl    = (float*)(smem + 151680);      // 32
  float* cstl     = (float*)(smem + 151808);      // 32
  unsigned* hn2   = (unsigned*)(smem + 151936);   // 16
  float* msc      = (float*)(smem + 152000);      // scratch

  const int tid = threadIdx.x;
  const int b = blockIdx.x & 15;
  const int s = blockIdx.x >> 4;

  // Wc[:,256:768] slice (128 pre-cols) as f16x2, gates-loop-friendly layout
  for (int i = 0; i < 128; ++i) {
    int idx = tid + i * 256;            // 0..32767 (uint index)
    int j = idx & 3, l = (idx >> 2) & 127, k2q = idx >> 9;
    int k2 = k2q * 4 + j;               // K-pair index, K = 256 + 2*k2
    int row = (l >> 5) * 256 + 32 * s + (l & 31);
    WcH[idx] = packh2(Wc[row * 768 + 256 + 2 * k2], Wc[row * 768 + 256 + 2 * k2 + 1]);
  }
  // Ws2 slice transposed-packed: [k2][c], k = 32s + 2*k2
  for (int i = 0; i < 16; ++i) {
    int idx = tid + i * 256;            // 0..4095
    int c = idx & 255, k2 = idx >> 8;
    W2H[idx] = packh2(Ws_w[c * 768 + 256 + 32 * s + 2 * k2],
                      Ws_w[c * 768 + 256 + 32 * s + 2 * k2 + 1]);
  }
  usl[tid] = Us_w[tid];
  const float usb = Us_b[0];
  if (tid < 32) cstl[tid] = 0.f;
  __syncthreads();

  const uint4* wp4 = (const uint4*)WcH;
  const uint4* av4p = (const uint4*)actH;

  for (int t = 0; t < T_LEN; ++t) {
    const int par = t & 1;

    // ---- stage 2: scores + unnormalized softmax partials ----
    hterml[tid] = gldf(&htermbuf[(par * 16 + b) * 256 + tid]);
    // zero rbuf/lbuf parity (1-par): last read at stage3(t-1), next add at stage2(t+1)
    if (tid < 32) gstf(&rbuf[((1 - par) * 16 + b) * 256 + 32 * s + tid], 0.f);
    if (s == 0 && tid == 0) gstf(&lbuf[(1 - par) * 16 + b], 0.f);
    __syncthreads();

    {
      int wv = tid >> 6, lane = tid & 63;
      float lsum = 0.f;
      for (int q = 0; q < 6; ++q) {
        int tp = 24 * s + wv * 6 + q;
        float4 bs = *(const float4*)&base[(tp * 16 + b) * 256 + lane * 4];
        float4 h4 = *(const float4*)&hterml[lane * 4];
        float4 u4 = *(const float4*)&usl[lane * 4];
        float p = u4.x * tanh_f(bs.x + h4.x) + u4.y * tanh_f(bs.y + h4.y)
                + u4.z * tanh_f(bs.z + h4.z) + u4.w * tanh_f(bs.w + h4.w);
        for (int off = 32; off >= 1; off >>= 1) p += __shfl_xor(p, off);
        if (lane == 0) {
          float e = __expf(p + usb);    // scores bounded (~|s|<6), no max-sub needed
          eel[wv * 6 + q] = e;
          lsum += e;
        }
      }
      if (lane == 0) gaddf(&lbuf[par * 16 + b], lsum);
    }
    __syncthreads();
    {
      float r = 0.f;
      for (int q = 0; q < 24; ++q)
        r = fmaf(eel[q], hs[((24 * s + q) * 16 + b) * 256 + tid], r);
      gaddf(&rbuf[(par * 16 + b) * 256 + tid], r);
    }
    dsyncA(&cnt[(b * 192 + t) * 2 + 0], 8);

    // ---- stage 3: gates ----
    if (tid == 0) msc[0] = 1.f / gldf(&lbuf[par * 16 + b]);
    {
      if (tid < 128) {                  // act K[0,256) = unnormalized Rt
        float a0 = gldf(&rbuf[(par * 16 + b) * 256 + 2 * tid]);
        float a1 = gldf(&rbuf[(par * 16 + b) * 256 + 2 * tid + 1]);
        actH[tid] = packh2(a0, a1);
      } else {                          // act K[256,512) = h_prev
        int k2l = tid - 128;
        float a0 = gldf(&ht[(par * 16 + b) * 256 + 2 * k2l]);
        float a1 = gldf(&ht[(par * 16 + b) * 256 + 2 * k2l + 1]);
        actH[tid] = packh2(a0, a1);
      }
    }
    // zero htermbuf[par] (all WGs of b finished reading it before dsync1)
    if (tid < 32) gstf(&htermbuf[(par * 16 + b) * 256 + 32 * s + tid], 0.f);
    __syncthreads();

    {
      int l = tid & 127, half = tid >> 7;
      float acc = 0.f;
      for (int k2q = 32 * half; k2q < 32 * half + 32; ++k2q) {
        uint4 wv4 = wp4[k2q * 128 + l];
        uint4 a4 = av4p[k2q];
        acc = fdot2(wv4.x, a4.x, acc);
        acc = fdot2(wv4.y, a4.y, acc);
        acc = fdot2(wv4.z, a4.z, acc);
        acc = fdot2(wv4.w, a4.w, acc);
      }
      prel[l * 2 + half] = acc;
    }
    __syncthreads();

    if (tid < 32) {
      int jl = tid;
      float inv = msc[0];
      int xb = (t * 16 + b) * 1024 + 32 * s + jl;
      float pi = xpre[xb + 0]   + prel[(0  + jl) * 2] * inv + prel[(0  + jl) * 2 + 1];
      float pf = xpre[xb + 256] + prel[(32 + jl) * 2] * inv + prel[(32 + jl) * 2 + 1];
      float pg = xpre[xb + 512] + prel[(64 + jl) * 2] * inv + prel[(64 + jl) * 2 + 1];
      float po = xpre[xb + 768] + prel[(96 + jl) * 2] * inv + prel[(96 + jl) * 2 + 1];
      float co = cstl[jl];
      float ig = sigm(pi), fg = sigm(pf), gg = tanh_f(pg), og = sigm(po);
      float cn = fmaf(fg, co, ig * gg);
      float h = og * tanh_f(cn);
      cstl[jl] = cn;
      hnewl[jl] = h;
      gstf(&ht[((1 - par) * 16 + b) * 256 + 32 * s + jl], h);
      out[(b * 192 + t) * 256 + 32 * s + jl] = h;
    }
    __syncthreads();
    if (tid < 16) hn2[tid] = packh2(hnewl[2 * tid], hnewl[2 * tid + 1]);
    __syncthreads();
    {
      float p2 = 0.f;
      for (int k2 = 0; k2 < 16; ++k2)
        p2 = fdot2(W2H[k2 * 256 + tid], hn2[k2], p2);
      gaddf(&htermbuf[((1 - par) * 16 + b) * 256 + tid], p2);
    }
    dsyncA(&cnt[(b * 192 + t) * 2 + 1], 8);
  }
}

extern "C" void kernel_launch(void* const* d_in, const int* in_sizes, int n_in,
                              void* d_out, int out_size, void* d_ws, size_t ws_size,
                              hipStream_t stream) {
  (void)in_sizes; (void)n_in; (void)out_size; (void)ws_size;
  const float* x    = (const float*)d_in[0];
  const float* W_ih = (const float*)d_in[1];
  const float* W_hh = (const float*)d_in[2];
  const float* b_l  = (const float*)d_in[3];
  const float* Ws_w = (const float*)d_in[4];
  const float* Ws_b = (const float*)d_in[5];
  const float* Us_w = (const float*)d_in[6];
  const float* Us_b = (const float*)d_in[7];
  const float* Wc   = (const float*)d_in[8];
  const float* bc   = (const float*)d_in[9];
  float* out = (float*)d_out;
  float* ws = (float*)d_ws;

  hipFuncSetAttribute((const void*)task_kernel,
                      hipFuncAttributeMaxDynamicSharedMemorySize, 160 * 1024);

  // zero exchange region + counters
  initk<<<64, 256, 0, stream>>>(ws + OFF_HT, INIT_WORDS);

  // X1 = x @ W_ih.T + b_lstm
  proj<<<dim3(32, 192), 256, 0, stream>>>(x, W_ih, b_l, ws + OFF_X1, 1024, 256, 0, 0);
  // xpre = x @ Wc[:, 0:256].T + bc
  proj<<<dim3(32, 192), 256, 0, stream>>>(x, Wc, bc, ws + OFF_XPRE, 1024, 768, 0, 0);
  // base = x @ Ws_w[:, 512:768].T + Ws_b
  proj<<<dim3(8, 192), 256, 0, stream>>>(x, Ws_w, Ws_b, ws + OFF_BASE, 256, 768, 512, 0);

  // shared LSTM -> hs (+ packed hx exchange)
  lstm_kernel<<<32, 256, 0, stream>>>(ws + OFF_X1, W_hh, ws + OFF_HS,
                                      (unsigned*)(ws + OFF_HX),
                                      (unsigned*)(ws + OFF_CNT));

  // base += hs @ Ws_w[:, 0:256].T
  proj<<<dim3(8, 192), 256, 0, stream>>>(ws + OFF_HS, Ws_w, nullptr, ws + OFF_BASE, 256, 768, 0, 1);

  // task loop
  task_kernel<<<128, 256, SMEM_TASK, stream>>>(
      ws + OFF_BASE, ws + OFF_XPRE, ws + OFF_HS, Us_w, Us_b, Wc, Ws_w,
      ws + OFF_HT, ws + OFF_HTERM, ws + OFF_RBUF, ws + OFF_LBUF,
      (unsigned*)(ws + OFF_CNT) + 192, out);
}

// Round 3
// 2341.987 us; speedup vs baseline: 2.5048x; 1.1041x over previous
//
#include <hip/hip_runtime.h>
#include <hip/hip_fp16.h>

#define T_LEN 192

// ws float offsets
#define OFF_X1    0          // X1T [192][1024][16]
#define OFF_XPRE  3145728    // [192][16][1024]
#define OFF_BASE  6291456    // [192][16][256]
#define OFF_HS    7077888    // [192][16][256]
#define OFF_HT    7864320    // f32 [16][256]        (no parity; ordered by flags)
#define OFF_RREC  7868416    // f32 [16][8][256]
#define OFF_HREC  7901184    // f32 [16][8][256]
#define OFF_LREC  7933952    // f32 [16][8] (pad 128)
#define OFF_HX    7934080    // u32 [2][2048]        (lstm h exchange, parity)
#define OFF_FL    7938176    // u32 [192][32]
#define OFF_FA    7944320    // u32 [16][192][8]
#define OFF_FB    7968896    // u32 [16][192][8]
#define INIT_WORDS 129152

#define SMEM_TASK 156416

typedef _Float16 h2_t __attribute__((ext_vector_type(2)));

__device__ __forceinline__ unsigned packh2(float a, float b){
  union { __half2 h; unsigned u; } v;
  v.h = __halves2half2(__float2half(a), __float2half(b));
  return v.u;
}
__device__ __forceinline__ float fdot2(unsigned a, unsigned b, float c){
#if __has_builtin(__builtin_amdgcn_fdot2)
  union { unsigned u; h2_t h; } ua, ub;
  ua.u = a; ub.u = b;
  return __builtin_amdgcn_fdot2(ua.h, ub.h, c, false);
#else
  union { unsigned u; __half2 h; } ua, ub;
  ua.u = a; ub.u = b;
  return c + __low2float(ua.h) * __low2float(ub.h)
           + __high2float(ua.h) * __high2float(ub.h);
#endif
}
__device__ __forceinline__ float tanh_f(float x){
  float cx = fminf(fmaxf(x, -15.f), 15.f);
  float e = __expf(2.f * cx);
  return (e - 1.f) / (e + 1.f);
}
__device__ __forceinline__ float sigm(float x){
  float cx = fminf(fmaxf(x, -30.f), 30.f);
  return 1.f / (1.f + __expf(-cx));
}

// relaxed agent-scope atomics: coherent at L3, no cache-maintenance
__device__ __forceinline__ float gldf(const float* p){
  return __hip_atomic_load(p, __ATOMIC_RELAXED, __HIP_MEMORY_SCOPE_AGENT);
}
__device__ __forceinline__ unsigned gldu(const unsigned* p){
  return __hip_atomic_load(p, __ATOMIC_RELAXED, __HIP_MEMORY_SCOPE_AGENT);
}
__device__ __forceinline__ void gstf(float* p, float v){
  __hip_atomic_store(p, v, __ATOMIC_RELAXED, __HIP_MEMORY_SCOPE_AGENT);
}
__device__ __forceinline__ void gstu(unsigned* p, unsigned v){
  __hip_atomic_store(p, v, __ATOMIC_RELAXED, __HIP_MEMORY_SCOPE_AGENT);
}

__global__ __launch_bounds__(256) void initk(float* p, int n){
  int i = blockIdx.x * blockDim.x + threadIdx.x;
  int stride = gridDim.x * blockDim.x;
  for (; i < n; i += stride) p[i] = 0.f;
}

// fused x-projections: bx<32 -> X1T (transposed), bx<64 -> xpre, else base-x
__global__ __launch_bounds__(256) void proj3(const float* __restrict__ x,
                                             const float* __restrict__ W_ih,
                                             const float* __restrict__ b_l,
                                             const float* __restrict__ Wc,
                                             const float* __restrict__ bc,
                                             const float* __restrict__ Ws_w,
                                             const float* __restrict__ Ws_b,
                                             float* __restrict__ ws){
  __shared__ float As[16 * 258];
  __shared__ float Wsh[256 * 34];
  const int bx = blockIdx.x, t = blockIdx.y, tid = threadIdx.x;
  const float* W; const float* bias; int ldw, woff, c0, mode; float* out;
  if (bx < 32)      { W = W_ih; bias = b_l;  ldw = 256; woff = 0;   c0 = bx * 32;        mode = 0; out = ws + OFF_X1; }
  else if (bx < 64) { W = Wc;   bias = bc;   ldw = 768; woff = 0;   c0 = (bx - 32) * 32; mode = 1; out = ws + OFF_XPRE; }
  else              { W = Ws_w; bias = Ws_b; ldw = 768; woff = 512; c0 = (bx - 64) * 32; mode = 2; out = ws + OFF_BASE; }

  for (int i = 0; i < 16; ++i)
    As[i * 258 + tid] = x[(t * 16 + i) * 256 + tid];
  for (int i = 0; i < 32; ++i)
    Wsh[tid * 34 + i] = W[(c0 + i) * ldw + woff + tid];
  __syncthreads();

  const int r = tid >> 4;
  const int c2 = (tid & 15) * 2;
  float acc0 = 0.f, acc1 = 0.f;
  for (int k = 0; k < 256; k += 2) {
    float2 a  = *(const float2*)&As[r * 258 + k];
    float2 w0 = *(const float2*)&Wsh[k * 34 + c2];
    float2 w1 = *(const float2*)&Wsh[(k + 1) * 34 + c2];
    acc0 = fmaf(a.x, w0.x, acc0); acc0 = fmaf(a.y, w1.x, acc0);
    acc1 = fmaf(a.x, w0.y, acc1); acc1 = fmaf(a.y, w1.y, acc1);
  }
  const int cg = c0 + c2;
  acc0 += bias[cg]; acc1 += bias[cg + 1];
  if (mode == 0) {                       // X1T [t][1024][16]
    out[(t * 1024 + cg) * 16 + r] = acc0;
    out[(t * 1024 + cg + 1) * 16 + r] = acc1;
  } else if (mode == 1) {
    float2 res; res.x = acc0; res.y = acc1;
    *(float2*)&out[(t * 16 + r) * 1024 + cg] = res;
  } else {
    float2 res; res.x = acc0; res.y = acc1;
    *(float2*)&out[(t * 16 + r) * 256 + cg] = res;
  }
}

// Shared LSTM: 32 WGs, WG w owns h-cols [8w,8w+8) for all 16 b.
// Per-WG flag sync (no contended atomic), X1T coalesced loads.
__global__ __launch_bounds__(256) void lstm_kernel(const float* __restrict__ X1T,
                                                   const float* __restrict__ W_hh,
                                                   float* __restrict__ hs,
                                                   unsigned* __restrict__ hx,
                                                   unsigned* __restrict__ fl){
  __shared__ unsigned Wl2[32 * 136];
  __shared__ unsigned hl2[16 * 136];
  __shared__ float prel[32 * 17];
  __shared__ float cl[128];
  const int tid = threadIdx.x;
  const int w = blockIdx.x;

  for (int i = 0; i < 16; ++i) {
    int idx = tid + i * 256;            // 0..4095
    int l = idx >> 7, k2 = idx & 127;
    int row = (l >> 3) * 256 + 8 * w + (l & 7);
    Wl2[l * 136 + k2] = packh2(W_hh[row * 256 + 2 * k2], W_hh[row * 256 + 2 * k2 + 1]);
  }
  if (tid < 128) cl[tid] = 0.f;
  __syncthreads();

  const int l0 = tid >> 4;
  const int l1 = l0 + 16;
  const int bb = tid & 15;
  const int colg0 = (l0 >> 3) * 256 + 8 * w + (l0 & 7);
  const int colg1 = (l1 >> 3) * 256 + 8 * w + (l1 & 7);

  for (int t = 0; t < T_LEN; ++t) {
    const int par = t & 1;

    if (t == 0) {
      for (int i = 0; i < 8; ++i) {
        int idx = tid + i * 256;
        hl2[(idx & 15) * 136 + (idx >> 4)] = 0u;
      }
    } else {
      for (int i = 0; i < 8; ++i) {
        int idx = tid + i * 256;
        hl2[(idx & 15) * 136 + (idx >> 4)] = gldu(&hx[par * 2048 + idx]);
      }
    }
    float acc0 = X1T[(t * 1024 + colg0) * 16 + bb];
    float acc1 = X1T[(t * 1024 + colg1) * 16 + bb];
    __syncthreads();

    {
      const uint4* wv0 = (const uint4*)&Wl2[l0 * 136];
      const uint4* wv1 = (const uint4*)&Wl2[l1 * 136];
      const uint4* hv  = (const uint4*)&hl2[bb * 136];
      for (int q = 0; q < 32; ++q) {
        uint4 h4 = hv[q];
        uint4 a4 = wv0[q];
        uint4 b4 = wv1[q];
        acc0 = fdot2(a4.x, h4.x, acc0); acc0 = fdot2(a4.y, h4.y, acc0);
        acc0 = fdot2(a4.z, h4.z, acc0); acc0 = fdot2(a4.w, h4.w, acc0);
        acc1 = fdot2(b4.x, h4.x, acc1); acc1 = fdot2(b4.y, h4.y, acc1);
        acc1 = fdot2(b4.z, h4.z, acc1); acc1 = fdot2(b4.w, h4.w, acc1);
      }
      prel[l0 * 17 + bb] = acc0;
      prel[l1 * 17 + bb] = acc1;
    }
    __syncthreads();

    if (tid < 128) {
      int j = tid & 7, b = tid >> 3;
      float pi = prel[(0  + j) * 17 + b];
      float pf = prel[(8  + j) * 17 + b];
      float pg = prel[(16 + j) * 17 + b];
      float po = prel[(24 + j) * 17 + b];
      float co = cl[tid];
      float ig = sigm(pi), fg = sigm(pf), gg = tanh_f(pg), og = sigm(po);
      float cn = fmaf(fg, co, ig * gg);
      float h = og * tanh_f(cn);
      cl[tid] = cn;
      hs[(t * 16 + b) * 256 + 8 * w + j] = h;
      float hnx = __shfl_down(h, 1);
      if ((j & 1) == 0)
        gstu(&hx[(1 - par) * 2048 + (4 * w + (j >> 1)) * 16 + b], packh2(h, hnx));
    }
    __syncthreads();             // drains hx stores (vmcnt0 before barrier)
    if (tid < 64) {
      if (tid == 0) gstu(&fl[t * 32 + w], 1u);
      while (__ballot((tid < 32) ? (gldu(&fl[t * 32 + tid]) != 0u) : 1) != 0xFFFFFFFFFFFFFFFFull) {}
    }
    __syncthreads();
  }
}

// Task loop: 128 WGs x 512 thr; b = bid&15 (co-XCD domain), s = bid>>4.
// Record-based exchange (pure stores) + per-WG flags; 2 syncs/step.
__global__ __launch_bounds__(512) void task_kernel(
    float* __restrict__ base, const float* __restrict__ xpre,
    const float* __restrict__ hs, const float* __restrict__ Us_w,
    const float* __restrict__ Us_b, const float* __restrict__ Wc,
    const float* __restrict__ Ws_w, float* __restrict__ ht,
    float* __restrict__ rrec, float* __restrict__ hrec,
    float* __restrict__ lrec, unsigned* __restrict__ fA,
    unsigned* __restrict__ fB, float* __restrict__ out){
  extern __shared__ char smem[];
  unsigned* WcH   = (unsigned*)smem;              // 131072 B
  unsigned* W2H   = (unsigned*)(smem + 131072);   // 16384 B
  unsigned* actH  = (unsigned*)(smem + 147456);   // 1024 B
  float* hterml   = (float*)(smem + 148480);      // 256
  float* usl      = (float*)(smem + 149504);      // 256
  float* eel      = (float*)(smem + 150528);      // 24 (pad 32)
  float* prel     = (float*)(smem + 150656);      // 128 x 4
  float* cstl     = (float*)(smem + 152832);      // 32
  unsigned* hn2   = (unsigned*)(smem + 152960);   // 16
  float* msc      = (float*)(smem + 153024);      // scratch

  const int tid = threadIdx.x;
  const int b = blockIdx.x & 15;
  const int s = blockIdx.x >> 4;

  // ---- fold base += hs @ Ws1^T for rows [24s,24s+24) of batch b (WG-local) ----
  {
    __half* Ws1T = (__half*)smem;                 // [k][c] stride 257
    float* hsf   = (float*)(smem + 131584);       // [24][258]
    for (int idx = tid; idx < 65536; idx += 512) {
      int c = idx >> 8, k = idx & 255;
      Ws1T[k * 257 + c] = __float2half(Ws_w[c * 768 + k]);
    }
    for (int idx = tid; idx < 6144; idx += 512) {
      int r = idx >> 8, k = idx & 255;
      hsf[r * 258 + k] = hs[((24 * s + r) * 16 + b) * 256 + k];
    }
    __syncthreads();
    {
      int c = tid & 255, hh = tid >> 8;
      float acc[12];
      #pragma unroll
      for (int j = 0; j < 12; ++j)
        acc[j] = base[((24 * s + hh * 12 + j) * 16 + b) * 256 + c];
      for (int k = 0; k < 256; ++k) {
        float wv = __half2float(Ws1T[k * 257 + c]);
        #pragma unroll
        for (int j = 0; j < 12; ++j)
          acc[j] = fmaf(hsf[(hh * 12 + j) * 258 + k], wv, acc[j]);
      }
      #pragma unroll
      for (int j = 0; j < 12; ++j)
        base[((24 * s + hh * 12 + j) * 16 + b) * 256 + c] = acc[j];
    }
    __syncthreads();
  }

  // ---- weight fills (overwrite fold scratch) ----
  for (int idx = tid; idx < 32768; idx += 512) {
    int j = idx & 3, l = (idx >> 2) & 127, k2q = idx >> 9;
    int k2 = k2q * 4 + j;
    int row = (l >> 5) * 256 + 32 * s + (l & 31);
    WcH[idx] = packh2(Wc[row * 768 + 256 + 2 * k2], Wc[row * 768 + 256 + 2 * k2 + 1]);
  }
  for (int idx = tid; idx < 4096; idx += 512) {
    int c = idx & 255, k2 = idx >> 8;
    W2H[idx] = packh2(Ws_w[c * 768 + 256 + 32 * s + 2 * k2],
                      Ws_w[c * 768 + 256 + 32 * s + 2 * k2 + 1]);
  }
  if (tid < 256) usl[tid] = Us_w[tid];
  if (tid < 32) cstl[tid] = 0.f;
  const float usb = Us_b[0];
  __syncthreads();

  const uint4* wp4 = (const uint4*)WcH;
  const uint4* av4 = (const uint4*)actH;

  for (int t = 0; t < T_LEN; ++t) {
    float hta = 0.f, htb = 0.f;
    float xp0 = 0.f, xp1 = 0.f, xp2 = 0.f, xp3 = 0.f;

    // ---- stage 2 prefetch: hterm (hrec sum), h_prev, xpre ----
    if (tid < 256) {
      float hsv = 0.f;
      #pragma unroll
      for (int i = 0; i < 8; ++i) hsv += gldf(&hrec[(b * 8 + i) * 256 + tid]);
      hterml[tid] = hsv;
      if (tid >= 128) {
        hta = gldf(&ht[b * 256 + 2 * (tid - 128)]);
        htb = gldf(&ht[b * 256 + 2 * (tid - 128) + 1]);
      }
    }
    if (tid < 32) {
      int xb = (t * 16 + b) * 1024 + 32 * s + tid;
      xp0 = xpre[xb];       xp1 = xpre[xb + 256];
      xp2 = xpre[xb + 512]; xp3 = xpre[xb + 768];
    }
    __syncthreads();

    // ---- scores: 8 waves x 3 rows ----
    {
      int wv = tid >> 6, lane = tid & 63;
      int tp0 = 24 * s + wv * 3;
      float4 h4 = *(const float4*)&hterml[lane * 4];
      float4 u4 = *(const float4*)&usl[lane * 4];
      float4 bs0 = *(const float4*)&base[((tp0 + 0) * 16 + b) * 256 + lane * 4];
      float4 bs1 = *(const float4*)&base[((tp0 + 1) * 16 + b) * 256 + lane * 4];
      float4 bs2 = *(const float4*)&base[((tp0 + 2) * 16 + b) * 256 + lane * 4];
      float p0 = u4.x * tanh_f(bs0.x + h4.x) + u4.y * tanh_f(bs0.y + h4.y)
               + u4.z * tanh_f(bs0.z + h4.z) + u4.w * tanh_f(bs0.w + h4.w);
      float p1 = u4.x * tanh_f(bs1.x + h4.x) + u4.y * tanh_f(bs1.y + h4.y)
               + u4.z * tanh_f(bs1.z + h4.z) + u4.w * tanh_f(bs1.w + h4.w);
      float p2 = u4.x * tanh_f(bs2.x + h4.x) + u4.y * tanh_f(bs2.y + h4.y)
               + u4.z * tanh_f(bs2.z + h4.z) + u4.w * tanh_f(bs2.w + h4.w);
      for (int off = 32; off >= 1; off >>= 1) {
        p0 += __shfl_xor(p0, off);
        p1 += __shfl_xor(p1, off);
        p2 += __shfl_xor(p2, off);
      }
      if (lane == 0) {
        eel[wv * 3 + 0] = __expf(p0 + usb);
        eel[wv * 3 + 1] = __expf(p1 + usb);
        eel[wv * 3 + 2] = __expf(p2 + usb);
      }
    }
    __syncthreads();

    // ---- Rt partial record + lsum record ----
    if (tid < 256) {
      float r = 0.f;
      #pragma unroll 8
      for (int q = 0; q < 24; ++q)
        r = fmaf(eel[q], hs[((24 * s + q) * 16 + b) * 256 + tid], r);
      gstf(&rrec[(b * 8 + s) * 256 + tid], r);
    } else if (tid == 256) {
      float lsum = 0.f;
      #pragma unroll
      for (int q = 0; q < 24; ++q) lsum += eel[q];
      gstf(&lrec[b * 8 + s], lsum);
    }
    __syncthreads();             // drain records
    {
      unsigned* fa = &fA[(b * 192 + t) * 8];
      if (tid < 64) {
        if (tid == 0) gstu(&fa[s], 1u);
        while (__ballot((tid < 8) ? (gldu(&fa[tid]) != 0u) : 1) != 0xFFFFFFFFFFFFFFFFull) {}
      }
    }
    __syncthreads();

    // ---- stage 3: act assembly ----
    if (tid == 0) {
      float L = 0.f;
      #pragma unroll
      for (int i = 0; i < 8; ++i) L += gldf(&lrec[b * 8 + i]);
      msc[0] = 1.f / L;
    }
    if (tid < 128) {
      float a0 = 0.f, a1 = 0.f;
      #pragma unroll
      for (int i = 0; i < 8; ++i) {
        a0 += gldf(&rrec[(b * 8 + i) * 256 + 2 * tid]);
        a1 += gldf(&rrec[(b * 8 + i) * 256 + 2 * tid + 1]);
      }
      actH[tid] = packh2(a0, a1);
    } else if (tid < 256) {
      actH[tid] = packh2(hta, htb);
    }
    __syncthreads();

    // ---- gates GEMV: l = tid&127, K-quarter = tid>>7 ----
    {
      int l = tid & 127, kq = tid >> 7;
      float acc = 0.f;
      #pragma unroll 4
      for (int k2q = 16 * kq; k2q < 16 * kq + 16; ++k2q) {
        uint4 wv4 = wp4[k2q * 128 + l];
        uint4 a4 = av4[k2q];
        acc = fdot2(wv4.x, a4.x, acc);
        acc = fdot2(wv4.y, a4.y, acc);
        acc = fdot2(wv4.z, a4.z, acc);
        acc = fdot2(wv4.w, a4.w, acc);
      }
      prel[l * 4 + kq] = acc;
    }
    __syncthreads();

    if (tid < 32) {
      int jl = tid;
      float inv = msc[0];
      float4 qi = *(const float4*)&prel[(0  + jl) * 4];
      float4 qf = *(const float4*)&prel[(32 + jl) * 4];
      float4 qg = *(const float4*)&prel[(64 + jl) * 4];
      float4 qo = *(const float4*)&prel[(96 + jl) * 4];
      float pi = xp0 + (qi.x + qi.y) * inv + qi.z + qi.w;
      float pf = xp1 + (qf.x + qf.y) * inv + qf.z + qf.w;
      float pg = xp2 + (qg.x + qg.y) * inv + qg.z + qg.w;
      float po = xp3 + (qo.x + qo.y) * inv + qo.z + qo.w;
      float co = cstl[jl];
      float ig = sigm(pi), fg = sigm(pf), gg = tanh_f(pg), og = sigm(po);
      float cn = fmaf(fg, co, ig * gg);
      float h = og * tanh_f(cn);
      cstl[jl] = cn;
      gstf(&ht[b * 256 + 32 * s + jl], h);
      out[(b * 192 + t) * 256 + 32 * s + jl] = h;
      float hnx = __shfl_down(h, 1);
      if ((jl & 1) == 0) hn2[jl >> 1] = packh2(h, hnx);
    }
    __syncthreads();

    // ---- hterm partial record from own h-slice ----
    if (tid < 256) {
      float p2s = 0.f;
      #pragma unroll
      for (int k2 = 0; k2 < 16; ++k2)
        p2s = fdot2(W2H[k2 * 256 + tid], hn2[k2], p2s);
      gstf(&hrec[(b * 8 + s) * 256 + tid], p2s);
    }
    __syncthreads();             // drain records
    {
      unsigned* fb = &fB[(b * 192 + t) * 8];
      if (tid < 64) {
        if (tid == 0) gstu(&fb[s], 1u);
        while (__ballot((tid < 8) ? (gldu(&fb[tid]) != 0u) : 1) != 0xFFFFFFFFFFFFFFFFull) {}
      }
    }
    __syncthreads();
  }
}

extern "C" void kernel_launch(void* const* d_in, const int* in_sizes, int n_in,
                              void* d_out, int out_size, void* d_ws, size_t ws_size,
                              hipStream_t stream) {
  (void)in_sizes; (void)n_in; (void)out_size; (void)ws_size;
  const float* x    = (const float*)d_in[0];
  const float* W_ih = (const float*)d_in[1];
  const float* W_hh = (const float*)d_in[2];
  const float* b_l  = (const float*)d_in[3];
  const float* Ws_w = (const float*)d_in[4];
  const float* Ws_b = (const float*)d_in[5];
  const float* Us_w = (const float*)d_in[6];
  const float* Us_b = (const float*)d_in[7];
  const float* Wc   = (const float*)d_in[8];
  const float* bc   = (const float*)d_in[9];
  float* out = (float*)d_out;
  float* ws = (float*)d_ws;

  hipFuncSetAttribute((const void*)task_kernel,
                      hipFuncAttributeMaxDynamicSharedMemorySize, 160 * 1024);

  // zero exchange region + flags
  initk<<<64, 256, 0, stream>>>(ws + OFF_HT, INIT_WORDS);

  // fused x-projections: X1T, xpre, base-x
  proj3<<<dim3(72, 192), 256, 0, stream>>>(x, W_ih, b_l, Wc, bc, Ws_w, Ws_b, ws);

  // shared LSTM -> hs (+ packed hx exchange)
  lstm_kernel<<<32, 256, 0, stream>>>(ws + OFF_X1, W_hh, ws + OFF_HS,
                                      (unsigned*)(ws + OFF_HX),
                                      (unsigned*)(ws + OFF_FL));

  // task loop (folds base += hs @ Ws1^T in its prologue)
  task_kernel<<<128, 512, SMEM_TASK, stream>>>(
      ws + OFF_BASE, ws + OFF_XPRE, ws + OFF_HS, Us_w, Us_b, Wc, Ws_w,
      ws + OFF_HT, ws + OFF_RREC, ws + OFF_HREC, ws + OFF_LREC,
      (unsigned*)(ws + OFF_FA), (unsigned*)(ws + OFF_FB), out);
}

// Round 4
// 1917.609 us; speedup vs baseline: 3.0591x; 1.2213x over previous
//
#include <hip/hip_runtime.h>
#include <hip/hip_fp16.h>

#define T_LEN 192

typedef unsigned long long u64;
typedef _Float16 f16x8 __attribute__((ext_vector_type(8)));
typedef float f32x4 __attribute__((ext_vector_type(4)));

// ws float offsets
#define OFF_X1F   0          // X1F [192][64 tile][16 b][16 row] f32
#define OFF_XPRE  3145728    // [192][16][1024]
#define OFF_XB3   6291456    // x@Ws3 + Ws_b  [192][16][256]
#define OFF_HSB   7077888    // hsB [16][192][256]
#define OFF_P     7864320    // u64 [16][8][192]
#define OFF_R     7913472    // u64 [16][256]
#define OFF_H     7921664    // u64 [16][256]
#define OFF_HX    7929856    // u64 [2][256][16]
#define EXCH_WORDS 81920

#define SMEM_TASK 156608

__device__ __forceinline__ unsigned packh2(float a, float b){
  union { __half2 h; unsigned u; } v;
  v.h = __halves2half2(__float2half(a), __float2half(b));
  return v.u;
}
__device__ __forceinline__ float2 unp2(unsigned u){
  union { unsigned u32; __half2 h; } v; v.u32 = u;
  return __half22float2(v.h);
}
__device__ __forceinline__ float fdot2(unsigned a, unsigned b, float c){
#if __has_builtin(__builtin_amdgcn_fdot2)
  typedef _Float16 h2t __attribute__((ext_vector_type(2)));
  union { unsigned u; h2t h; } ua, ub;
  ua.u = a; ub.u = b;
  return __builtin_amdgcn_fdot2(ua.h, ub.h, c, false);
#else
  float2 x = unp2(a), y = unp2(b);
  return c + x.x*y.x + x.y*y.y;
#endif
}
__device__ __forceinline__ float tanh_f(float x){
  float cx = fminf(fmaxf(x, -15.f), 15.f);
  float e = __expf(2.f * cx);
  return (e - 1.f) / (e + 1.f);
}
__device__ __forceinline__ float sigm(float x){
  float cx = fminf(fmaxf(x, -30.f), 30.f);
  return 1.f / (1.f + __expf(-cx));
}

__device__ __forceinline__ u64 gld64(const u64* p){
  return __hip_atomic_load(p, __ATOMIC_RELAXED, __HIP_MEMORY_SCOPE_AGENT);
}
__device__ __forceinline__ void gst64(u64* p, u64 v){
  __hip_atomic_store(p, v, __ATOMIC_RELAXED, __HIP_MEMORY_SCOPE_AGENT);
}

__global__ __launch_bounds__(256) void initk(float* p, int n){
  int i = blockIdx.x * blockDim.x + threadIdx.x;
  int stride = gridDim.x * blockDim.x;
  for (; i < n; i += stride) p[i] = 0.f;
}

// fused x-projections: bx<32 -> X1F (MFMA-fragment layout), bx<64 -> xpre, else xb3
__global__ __launch_bounds__(256) void proj3(const float* __restrict__ x,
                                             const float* __restrict__ W_ih,
                                             const float* __restrict__ b_l,
                                             const float* __restrict__ Wc,
                                             const float* __restrict__ bc,
                                             const float* __restrict__ Ws_w,
                                             const float* __restrict__ Ws_b,
                                             float* __restrict__ ws){
  __shared__ float As[16 * 258];
  __shared__ float Wsh[256 * 34];
  const int bx = blockIdx.x, t = blockIdx.y, tid = threadIdx.x;
  const float* W; const float* bias; int ldw, woff, c0, mode; float* out;
  if (bx < 32)      { W = W_ih; bias = b_l;  ldw = 256; woff = 0;   c0 = bx * 32;        mode = 0; out = ws + OFF_X1F; }
  else if (bx < 64) { W = Wc;   bias = bc;   ldw = 768; woff = 0;   c0 = (bx - 32) * 32; mode = 1; out = ws + OFF_XPRE; }
  else              { W = Ws_w; bias = Ws_b; ldw = 768; woff = 512; c0 = (bx - 64) * 32; mode = 2; out = ws + OFF_XB3; }

  for (int i = 0; i < 16; ++i)
    As[i * 258 + tid] = x[(t * 16 + i) * 256 + tid];
  for (int i = 0; i < 32; ++i)
    Wsh[tid * 34 + i] = W[(c0 + i) * ldw + woff + tid];
  __syncthreads();

  const int r = tid >> 4;          // batch row within t
  const int c2 = (tid & 15) * 2;
  float acc0 = 0.f, acc1 = 0.f;
  for (int k = 0; k < 256; k += 2) {
    float2 a  = *(const float2*)&As[r * 258 + k];
    float2 w0 = *(const float2*)&Wsh[k * 34 + c2];
    float2 w1 = *(const float2*)&Wsh[(k + 1) * 34 + c2];
    acc0 = fmaf(a.x, w0.x, acc0); acc0 = fmaf(a.y, w1.x, acc0);
    acc1 = fmaf(a.x, w0.y, acc1); acc1 = fmaf(a.y, w1.y, acc1);
  }
  const int cg = c0 + c2;
  acc0 += bias[cg]; acc1 += bias[cg + 1];
  float2 res; res.x = acc0; res.y = acc1;
  if (mode == 0) {
    // X1F[t][tile = cg>>4][b = r][row = cg&15]; cg even so cg,cg+1 same tile
    *(float2*)&out[((t * 64 + (cg >> 4)) * 16 + r) * 16 + (cg & 15)] = res;
  } else if (mode == 1) {
    *(float2*)&out[(t * 16 + r) * 1024 + cg] = res;
  } else {
    *(float2*)&out[(t * 16 + r) * 256 + cg] = res;
  }
}

// Shared LSTM: 2 WGs x 512 thr; W_hh resident in VGPRs, MFMA 16x16x32_f16.
// WG wg owns h-cols [wg*128, wg*128+128). Wave = j-block of 16 cols, all 4 gates.
// D[row=precol-local=quad*4+r][col=b=lane&15]; A=W[m=lane&15][k=quad*8+j];
// B=h^T: lane reads hT[b=lane&15][k=kk*32+quad*8 ..+8].
__global__ __launch_bounds__(512) void lstm_kernel(const float* __restrict__ X1F,
                                                   const float* __restrict__ W_hh,
                                                   float* __restrict__ hsB,
                                                   u64* __restrict__ hx){
  __shared__ unsigned hT[16 * 136];   // [b][k2], row stride 136 u32 (16B-aligned)
  const int tid = threadIdx.x;
  const int wg = blockIdx.x;
  const int wave = tid >> 6, lane = tid & 63;
  const int b16 = lane & 15, quad = lane >> 4;
  const int jb = wg * 8 + wave;       // j-block 0..15
  const int peer0 = (1 - wg) * 128;

  // W fragments -> VGPRs (once)
  f16x8 wf[4][8];
  #pragma unroll
  for (int g = 0; g < 4; ++g) {
    #pragma unroll
    for (int kk = 0; kk < 8; ++kk) {
      int row = g * 256 + jb * 16 + b16;
      const float* wp = &W_hh[row * 256 + kk * 32 + quad * 8];
      f16x8 v;
      #pragma unroll
      for (int j = 0; j < 8; ++j) v[j] = (_Float16)wp[j];
      wf[g][kk] = v;
    }
  }
  for (int i = tid; i < 16 * 136; i += 512) hT[i] = 0u;
  float cst[4] = {0.f, 0.f, 0.f, 0.f};
  __syncthreads();

  for (int t = 0; t < T_LEN; ++t) {
    // prefetch X1 (C init) — independent of h
    float4 xi[4];
    #pragma unroll
    for (int g = 0; g < 4; ++g)
      xi[g] = *(const float4*)&X1F[((t * 64 + g * 16 + jb) * 16 + b16) * 16 + quad * 4];

    if (t > 0) {
      const u64* src = &hx[((u64)((t - 1) & 1) * 256) * 16];
      #pragma unroll
      for (int cc = 0; cc < 2; ++cc) {
        int idx = tid * 2 + cc;         // 0..1023: peer cells
        int jp = idx >> 4, bbq = idx & 15;
        int j0 = peer0 + jp * 2;
        u64 v0, v1;
        for (;;) {
          v0 = gld64(&src[(j0) * 16 + bbq]);
          v1 = gld64(&src[(j0 + 1) * 16 + bbq]);
          if ((unsigned)v0 == (unsigned)t && (unsigned)v1 == (unsigned)t) break;
        }
        hT[bbq * 136 + (j0 >> 1)] =
            packh2(__uint_as_float((unsigned)(v0 >> 32)),
                   __uint_as_float((unsigned)(v1 >> 32)));
      }
    }
    __syncthreads();     // hT(t-1) complete (own half from prev epilogue)

    f32x4 acc[4];
    #pragma unroll
    for (int g = 0; g < 4; ++g) {
      f32x4 a; a[0]=xi[g].x; a[1]=xi[g].y; a[2]=xi[g].z; a[3]=xi[g].w;
      acc[g] = a;
    }
    #pragma unroll
    for (int kk = 0; kk < 8; ++kk) {
      union { uint4 u; f16x8 h; } bv;
      bv.u = *(const uint4*)&hT[b16 * 136 + kk * 16 + quad * 4];
      #pragma unroll
      for (int g = 0; g < 4; ++g)
        acc[g] = __builtin_amdgcn_mfma_f32_16x16x32_f16(wf[g][kk], bv.h, acc[g], 0, 0, 0);
    }
    __syncthreads();     // all hT reads done before overwrite

    float hv[4];
    #pragma unroll
    for (int r = 0; r < 4; ++r) {
      float pi = acc[0][r], pf = acc[1][r], pg = acc[2][r], po = acc[3][r];
      float cn = fmaf(sigm(pf), cst[r], sigm(pi) * tanh_f(pg));
      hv[r] = sigm(po) * tanh_f(cn);
      cst[r] = cn;
    }
    int j0 = jb * 16 + quad * 4;
    *(float4*)&hsB[(b16 * 192 + t) * 256 + j0] = make_float4(hv[0], hv[1], hv[2], hv[3]);
    hT[b16 * 136 + (j0 >> 1)]     = packh2(hv[0], hv[1]);
    hT[b16 * 136 + (j0 >> 1) + 1] = packh2(hv[2], hv[3]);
    u64* dst = &hx[((u64)(t & 1) * 256) * 16];
    #pragma unroll
    for (int r = 0; r < 4; ++r)
      gst64(&dst[(j0 + r) * 16 + b16],
            ((u64)__float_as_uint(hv[r]) << 32) | (unsigned)(t + 1));
    // next-iter post-poll barrier orders own hT writes vs next reads
  }
}

// Task loop: 128 WGs x 1024 thr; b = bid&15, s = bid>>4 owns c in [32s,32s+32).
// 3 seq-embedded exchanges/step (p scores, R final-normalized, h), all 1-RTT polls.
__global__ __launch_bounds__(1024) void task_kernel(
    const float* __restrict__ xb3, const float* __restrict__ xpre,
    const float* __restrict__ hsB, const float* __restrict__ Us_w,
    const float* __restrict__ Us_b, const float* __restrict__ Wc,
    const float* __restrict__ Ws_w,
    u64* __restrict__ Pbuf, u64* __restrict__ Rbuf, u64* __restrict__ Hbuf,
    float* __restrict__ out){
  extern __shared__ char smem[];
  // prologue views
  unsigned* hsL  = (unsigned*)smem;               // [192][129] u32 (f16x2)
  unsigned* Ws1L = (unsigned*)(smem + 99072);     // [32][129]
  float*    baseS= (float*)(smem + 115584);       // [192][33]
  // main views
  unsigned* WcH  = (unsigned*)smem;               // 32768 u32
  unsigned* Ws2L = (unsigned*)(smem + 131072);    // [32][130]
  float* scr     = (float*)(smem + 147712);       // [32][33] union
  float* prel    = (float*)(smem + 147712);       // [128][8] (same region, disjoint phase)
  float* eel     = (float*)(smem + 151936);       // 192
  float* rl      = (float*)(smem + 152704);       // 256
  float* hl      = (float*)(smem + 153728);       // 256
  unsigned* h2l  = (unsigned*)(smem + 154752);    // 128
  unsigned* actH = (unsigned*)(smem + 155264);    // 256: [R pairs | h pairs]
  float* hterml  = (float*)(smem + 156288);       // 32
  float* usl     = (float*)(smem + 156416);       // 32
  float* msc     = (float*)(smem + 156544);

  const int tid = threadIdx.x;
  const int bb = blockIdx.x & 15;
  const int s  = blockIdx.x >> 4;

  // ---- prologue P1: stage hs (f16) + Ws1 slice ----
  for (int idx = tid; idx < 24576; idx += 1024) {
    int tp = idx >> 7, k2 = idx & 127;
    const float* hp = &hsB[(bb * 192 + tp) * 256 + 2 * k2];
    hsL[tp * 129 + k2] = packh2(hp[0], hp[1]);
  }
  for (int idx = tid; idx < 4096; idx += 1024) {
    int c = idx >> 7, k2 = idx & 127;
    const float* wp = &Ws_w[(32 * s + c) * 768 + 2 * k2];
    Ws1L[c * 129 + k2] = packh2(wp[0], wp[1]);
  }
  __syncthreads();
  // ---- P2: base_s = xb3 + hs @ Ws1^T for [192 tp][own 32 c] ----
  {
    int c = tid & 31, g = tid >> 5;
    float a6[6];
    #pragma unroll
    for (int j = 0; j < 6; ++j)
      a6[j] = xb3[((g * 6 + j) * 16 + bb) * 256 + 32 * s + c];
    for (int k2 = 0; k2 < 128; ++k2) {
      unsigned wv = Ws1L[c * 129 + k2];
      #pragma unroll
      for (int j = 0; j < 6; ++j)
        a6[j] = fdot2(wv, hsL[(g * 6 + j) * 129 + k2], a6[j]);
    }
    #pragma unroll
    for (int j = 0; j < 6; ++j)
      baseS[(g * 6 + j) * 33 + c] = a6[j];
  }
  __syncthreads();
  // ---- P3: persistent registers: base (f16 pairs), hs for R ----
  unsigned bs4[4] = {0u, 0u, 0u, 0u};
  if (tid < 768) {
    int tp = tid >> 2, q = tid & 3;
    #pragma unroll
    for (int j2 = 0; j2 < 4; ++j2)
      bs4[j2] = packh2(baseS[tp * 33 + q * 8 + 2 * j2],
                       baseS[tp * 33 + q * 8 + 2 * j2 + 1]);
  }
  float hsr[6];
  {
    int c = tid & 31, g = tid >> 5;
    #pragma unroll
    for (int j = 0; j < 6; ++j)
      hsr[j] = hsB[(bb * 192 + g * 6 + j) * 256 + 32 * s + c];
  }
  __syncthreads();
  // ---- P4: main weight fills (overwrite prologue regions) ----
  for (int idx = tid; idx < 32768; idx += 1024) {
    int j = idx & 3, l = (idx >> 2) & 127, k2q = idx >> 9;
    int k2 = k2q * 4 + j;
    int row = (l >> 5) * 256 + 32 * s + (l & 31);
    const float* wp = &Wc[row * 768 + 256 + 2 * k2];
    WcH[idx] = packh2(wp[0], wp[1]);
  }
  for (int idx = tid; idx < 4096; idx += 1024) {
    int c = idx >> 7, k2 = idx & 127;
    const float* wp = &Ws_w[(32 * s + c) * 768 + 256 + 2 * k2];
    Ws2L[c * 130 + k2] = packh2(wp[0], wp[1]);
  }
  if (tid < 32) usl[tid] = Us_w[32 * s + tid];
  const float usb = Us_b[0];
  __syncthreads();

  u64* Pb = Pbuf + (bb * 8) * 192;
  u64* Rb = Rbuf + bb * 256;
  u64* Hb = Hbuf + bb * 256;
  const uint4* wp4 = (const uint4*)WcH;
  const uint4* av4 = (const uint4*)actH;
  float creg = 0.f;       // c-state (tid<32)

  for (int t = 0; t < T_LEN; ++t) {
    const unsigned seq = (unsigned)(t + 1);
    float xp0 = 0.f, xp1 = 0.f, xp2 = 0.f, xp3 = 0.f;
    if (tid < 32) {
      const float* xq = &xpre[(t * 16 + bb) * 1024 + 32 * s + tid];
      xp0 = xq[0]; xp1 = xq[256]; xp2 = xq[512]; xp3 = xq[768];
    }
    // S1: h(t-1) poll (single u64 per thread)
    if (tid < 256) {
      float hvv = 0.f;
      if (t > 0) {
        u64 v;
        do { v = gld64(&Hb[tid]); } while ((unsigned)v != (unsigned)t);
        hvv = __uint_as_float((unsigned)(v >> 32));
      }
      hl[tid] = hvv;
    }
    __syncthreads();                 // B1
    if (tid < 128) {
      unsigned u = packh2(hl[2 * tid], hl[2 * tid + 1]);
      h2l[tid] = u; actH[128 + tid] = u;
    }
    __syncthreads();                 // B2
    // S3: hterm_s = Ws2[c-slice,:] @ h  (local, no exchange)
    {
      int c = tid & 31, seg = tid >> 5;
      float a = 0.f;
      #pragma unroll
      for (int i = 0; i < 4; ++i)
        a = fdot2(Ws2L[c * 130 + seg * 4 + i], h2l[seg * 4 + i], a);
      scr[c * 33 + seg] = a;
    }
    __syncthreads();                 // B3
    if (tid < 32) {
      float a = 0.f;
      #pragma unroll 8
      for (int i = 0; i < 32; ++i) a += scr[tid * 33 + i];
      hterml[tid] = a;
    }
    __syncthreads();                 // B4
    // S5: score partials over own 32 c for all 192 tp; publish p_s
    if (tid < 768) {
      int tp = tid >> 2, q = tid & 3;
      float p = 0.f;
      #pragma unroll
      for (int m = 0; m < 4; ++m) {
        float2 bv = unp2(bs4[m]);
        int c0 = q * 8 + 2 * m;
        p += usl[c0]     * tanh_f(bv.x + hterml[c0]);
        p += usl[c0 + 1] * tanh_f(bv.y + hterml[c0 + 1]);
      }
      p += __shfl_xor(p, 1);
      p += __shfl_xor(p, 2);
      if ((tid & 3) == 0)
        gst64(&Pb[s * 192 + tp], ((u64)__float_as_uint(p) << 32) | seq);
    }
    // S6: p poll + exp (bounded scores, no max-sub)
    if (tid < 192) {
      u64 v[8];
      for (;;) {
        bool ok = true;
        #pragma unroll
        for (int sp = 0; sp < 8; ++sp) {
          v[sp] = gld64(&Pb[sp * 192 + tid]);
          ok &= ((unsigned)v[sp] == seq);
        }
        if (ok) break;
      }
      float sum = 0.f;
      #pragma unroll
      for (int sp = 0; sp < 8; ++sp) sum += __uint_as_float((unsigned)(v[sp] >> 32));
      eel[tid] = __expf(sum + usb);
    }
    __syncthreads();                 // B5
    // S7: L-reduce (wave0) + R partial (all, hs in regs)
    if (tid < 64) {
      float a = eel[tid] + eel[tid + 64] + eel[tid + 128];
      #pragma unroll
      for (int off = 32; off >= 1; off >>= 1) a += __shfl_xor(a, off);
      if (tid == 0) msc[0] = 1.f / a;
    }
    {
      int c = tid & 31, g = tid >> 5;
      float a = 0.f;
      #pragma unroll
      for (int j = 0; j < 6; ++j) a = fmaf(eel[g * 6 + j], hsr[j], a);
      scr[g * 33 + c] = a;
    }
    __syncthreads();                 // B6
    if (tid < 32) {
      float a = 0.f;
      #pragma unroll 8
      for (int g = 0; g < 32; ++g) a += scr[g * 33 + tid];
      a *= msc[0];                   // final normalized R slice
      gst64(&Rb[32 * s + tid], ((u64)__float_as_uint(a) << 32) | seq);
    }
    // S9: R poll (1 u64/thread)
    if (tid < 256) {
      u64 v;
      do { v = gld64(&Rb[tid]); } while ((unsigned)v != seq);
      rl[tid] = __uint_as_float((unsigned)(v >> 32));
    }
    __syncthreads();                 // B7
    if (tid < 128) actH[tid] = packh2(rl[2 * tid], rl[2 * tid + 1]);
    __syncthreads();                 // B8
    // S11: gates GEMV (K=512 f16): l = tid&127, K-eighth = tid>>7
    {
      int l = tid & 127, kq = tid >> 7;
      float a = 0.f;
      #pragma unroll
      for (int i = 0; i < 8; ++i) {
        uint4 w4 = wp4[(kq * 8 + i) * 128 + l];
        uint4 a4 = av4[kq * 8 + i];
        a = fdot2(w4.x, a4.x, a); a = fdot2(w4.y, a4.y, a);
        a = fdot2(w4.z, a4.z, a); a = fdot2(w4.w, a4.w, a);
      }
      prel[l * 8 + kq] = a;
    }
    __syncthreads();                 // B9
    if (tid < 32) {
      float pr[4];
      #pragma unroll
      for (int g = 0; g < 4; ++g) {
        const float4* pp = (const float4*)&prel[(g * 32 + tid) * 8];
        float4 p0 = pp[0], p1 = pp[1];
        pr[g] = p0.x + p0.y + p0.z + p0.w + p1.x + p1.y + p1.z + p1.w;
      }
      pr[0] += xp0; pr[1] += xp1; pr[2] += xp2; pr[3] += xp3;
      float cn = fmaf(sigm(pr[1]), creg, sigm(pr[0]) * tanh_f(pr[2]));
      float hh = sigm(pr[3]) * tanh_f(cn);
      creg = cn;
      out[(bb * 192 + t) * 256 + 32 * s + tid] = hh;
      gst64(&Hb[32 * s + tid], ((u64)__float_as_uint(hh) << 32) | seq);
    }
  }
}

extern "C" void kernel_launch(void* const* d_in, const int* in_sizes, int n_in,
                              void* d_out, int out_size, void* d_ws, size_t ws_size,
                              hipStream_t stream) {
  (void)in_sizes; (void)n_in; (void)out_size; (void)ws_size;
  const float* x    = (const float*)d_in[0];
  const float* W_ih = (const float*)d_in[1];
  const float* W_hh = (const float*)d_in[2];
  const float* b_l  = (const float*)d_in[3];
  const float* Ws_w = (const float*)d_in[4];
  const float* Ws_b = (const float*)d_in[5];
  const float* Us_w = (const float*)d_in[6];
  const float* Us_b = (const float*)d_in[7];
  const float* Wc   = (const float*)d_in[8];
  const float* bc   = (const float*)d_in[9];
  float* out = (float*)d_out;
  float* ws = (float*)d_ws;

  hipFuncSetAttribute((const void*)task_kernel,
                      hipFuncAttributeMaxDynamicSharedMemorySize, 160 * 1024);

  // zero exchange region (P, R, H, HX — seq tags restart at 1 each launch)
  initk<<<64, 256, 0, stream>>>(ws + OFF_P, EXCH_WORDS);

  // fused x-projections: X1F, xpre, xb3
  proj3<<<dim3(72, 192), 256, 0, stream>>>(x, W_ih, b_l, Wc, bc, Ws_w, Ws_b, ws);

  // shared LSTM: 2 persistent WGs, W_hh in VGPRs via MFMA
  lstm_kernel<<<2, 512, 0, stream>>>(ws + OFF_X1F, W_hh, ws + OFF_HSB,
                                     (u64*)(ws + OFF_HX));

  // task loop
  task_kernel<<<128, 1024, SMEM_TASK, stream>>>(
      ws + OFF_XB3, ws + OFF_XPRE, ws + OFF_HSB, Us_w, Us_b, Wc, Ws_w,
      (u64*)(ws + OFF_P), (u64*)(ws + OFF_R), (u64*)(ws + OFF_H), out);
}